// Round 6
// baseline (379.172 us; speedup 1.0000x reference)
//
#include <hip/hip_runtime.h>
#include <hip/hip_bf16.h>
#include <math.h>

// B=8, P=2048, Q=1024, H=1024
// Pipeline: convert -> fused proj (pkey,qkey) -> scores -> transpose ->
//           softmax -> ctx.
//
// GEMM (R6): faithful m201-style PER-PHASE schedule. 256x256 tile, BK=64,
// 512 thr = 8 waves (2M x 4N), per-wave 128x64 (acc[8][4]). 2 LDS slots x
// 64KB = 128KB. Per K-tile, 4 phases, each:
//   { ds_read subtile (12/4/8/0 x b128) ; stage half-tile of kt+1 (ph1/ph2,
//     4 x global_load_lds) ; s_barrier ; lgkmcnt(0)+sched_barrier ;
//     setprio(1) ; 16 MFMA (one C-quadrant) ; setprio(0) ; s_barrier }
// ph4 ends with vmcnt(0) (own slices of tile kt+1, issued ~3 phases earlier
// in ph1/ph2 -> ~600cyc cover, no mid-tile drain) + barrier (publishes all
// waves' slices before next ph1's ds_reads).
// R1-R5 synced once/twice per K-tile with monolithic MFMA bursts = exactly
// the m196 losing variants ("coarse phase-split without fine interleave
// HURTS"); the per-phase double-barrier is the documented 912->1563 lever
// and the regime-gate for swizzle+setprio to pay.
// LDS XOR swizzle both-sides (verified R2-R5): phys 16B-slot = logical ^
// (row&7); staging pre-swizzles the GLOBAL col (LDS dest stays linear for
// global_load_lds); sa0/sa1 on read.
// NT-fastest decode + XCD chunking (R5): A-panels once, B L2-resident.

typedef _Float16 v8h __attribute__((ext_vector_type(8)));
typedef _Float16 v4h __attribute__((ext_vector_type(4)));
typedef float v4f __attribute__((ext_vector_type(4)));

#define AS1C(p) ((const __attribute__((address_space(1))) void*)(p))
#define AS3(p)  ((__attribute__((address_space(3))) void*)(p))

// ---------------------------------------------------------------------------
// NT MFMA GEMM: C[m,n] = sum_k A[m,k]*B[n,k], A:[M,K] B:[N,K] row-major f16.
// Grid multiple of 8; tiles 256x256; K%64==0, K>=128.
// mt >= mtSplit switches to {B2, Ch2} with re-based output row (A contiguous).
__global__ __launch_bounds__(512) void gemm_nt_f16_256(
    const _Float16* __restrict__ A, const _Float16* __restrict__ B,
    float* __restrict__ Cf, _Float16* __restrict__ Ch,
    const _Float16* __restrict__ B2, _Float16* __restrict__ Ch2, int mtSplit,
    int N, int K, int Mtiles, int Ntiles,
    long long sA, long long sB, long long sC, int relu)
{
  extern __shared__ _Float16 lds[];   // 2 slots x (A 16384 | B 16384) f16

  const int nwg = gridDim.x;
  const int cpx = nwg >> 3;
  const int bid = (blockIdx.x & 7) * cpx + (blockIdx.x >> 3);
  const int nt  = bid % Ntiles;
  const int mt  = (bid / Ntiles) % Mtiles;
  const int bz  = bid / (Mtiles * Ntiles);

  A += (long long)bz * sA;

  const _Float16* Bp = B;
  _Float16* Chp = Ch;
  int m0c = mt * 256;
  if (mt >= mtSplit) { Bp = B2; Chp = Ch2; m0c = (mt - mtSplit) * 256; }
  Bp += (long long)bz * sB;

  const int m0g = mt * 256;
  const int n0  = nt * 256;
  const int t   = threadIdx.x;        // 0..511
  const int l   = t & 63;
  const int w   = t >> 6;             // 0..7
  const int wm  = (w >> 2) * 128;     // 0 or 128
  const int wn  = (w & 3) * 64;       // 0,64,128,192
  const int fr  = l & 15;
  const int fq  = l >> 4;
  const int r3  = fr & 7;
  const int sa0 = (fq ^ r3) * 8;        // kh=0 swizzled 16B-slot (f16 elems)
  const int sa1 = ((4 + fq) ^ r3) * 8;  // kh=1

  // Staging: each global_load_lds covers 64 rows x 128B (512 thr x 16B).
  // Thread t: row-in-chunk = t>>3 (0..63), phys slot = t&7,
  // pre-swizzled global col = ((t&7) ^ (row&7))*8.
  const int trow = t >> 3;
  const int tswz = ((t & 7) ^ (trow & 7)) * 8;

  const _Float16* Ast = A  + (long long)(m0g + trow) * K + tswz;
  const _Float16* Bst = Bp + (long long)(n0  + trow) * K + tswz;

  v4f acc[8][4];
#pragma unroll
  for (int i = 0; i < 8; ++i)
#pragma unroll
    for (int j = 0; j < 4; ++j)
      acc[i][j] = (v4f){0.f, 0.f, 0.f, 0.f};

  const int NT = K >> 6;

  // half h of tile kt: A rows h*128..h*128+127 + B rows h*128..h*128+127
  // LDS slot (kt&1): A region [0,16384), B region [16384,32768), row*64.
#define STAGE_HALF(kt, h) do {                                                            \
    _Float16* s_ = lds + (((kt) & 1) * 32768) + (h) * 8192;                               \
    const long long ko_ = (long long)((kt) << 6);                                         \
    const long long ro_ = (long long)((h) * 128);                                         \
    __builtin_amdgcn_global_load_lds(AS1C(Ast + ro_ * K + ko_),        AS3(s_ +         t * 8), 16, 0, 0); \
    __builtin_amdgcn_global_load_lds(AS1C(Ast + (ro_ + 64) * K + ko_), AS3(s_ +  4096 + t * 8), 16, 0, 0); \
    __builtin_amdgcn_global_load_lds(AS1C(Bst + ro_ * K + ko_),        AS3(s_ + 16384 + t * 8), 16, 0, 0); \
    __builtin_amdgcn_global_load_lds(AS1C(Bst + (ro_ + 64) * K + ko_), AS3(s_ + 20480 + t * 8), 16, 0, 0); \
  } while (0)

  // Prologue: tile 0 fully staged, drained, published.
  STAGE_HALF(0, 0);
  STAGE_HALF(0, 1);
  asm volatile("s_waitcnt vmcnt(0)" ::: "memory");
  __builtin_amdgcn_sched_barrier(0);
  __builtin_amdgcn_s_barrier();

  for (int kt = 0; kt < NT; ++kt) {
    const _Float16* Ab = lds + ((kt & 1) * 32768);
    const _Float16* Bb = Ab + 16384;

    v8h a0[4], a1[4], b0[4], b1[4];

    // ---------------- phase 1: quadrant (i0-3, j0-1), 12 ds_reads ----------
#pragma unroll
    for (int i = 0; i < 4; ++i) {
      a0[i] = *(const v8h*)&Ab[(wm + i * 16 + fr) * 64 + sa0];
      a1[i] = *(const v8h*)&Ab[(wm + i * 16 + fr) * 64 + sa1];
    }
#pragma unroll
    for (int j = 0; j < 2; ++j) {
      b0[j] = *(const v8h*)&Bb[(wn + j * 16 + fr) * 64 + sa0];
      b1[j] = *(const v8h*)&Bb[(wn + j * 16 + fr) * 64 + sa1];
    }
    if (kt + 1 < NT) STAGE_HALF(kt + 1, 0);
    __builtin_amdgcn_s_barrier();
    asm volatile("s_waitcnt lgkmcnt(0)" ::: "memory");
    __builtin_amdgcn_sched_barrier(0);
    __builtin_amdgcn_s_setprio(1);
#pragma unroll
    for (int i = 0; i < 4; ++i)
#pragma unroll
      for (int j = 0; j < 2; ++j) {
        acc[i][j] = __builtin_amdgcn_mfma_f32_16x16x32_f16(a0[i], b0[j], acc[i][j], 0, 0, 0);
        acc[i][j] = __builtin_amdgcn_mfma_f32_16x16x32_f16(a1[i], b1[j], acc[i][j], 0, 0, 0);
      }
    __builtin_amdgcn_s_setprio(0);
    __builtin_amdgcn_s_barrier();

    // ---------------- phase 2: quadrant (i0-3, j2-3), 4 ds_reads -----------
#pragma unroll
    for (int j = 2; j < 4; ++j) {
      b0[j] = *(const v8h*)&Bb[(wn + j * 16 + fr) * 64 + sa0];
      b1[j] = *(const v8h*)&Bb[(wn + j * 16 + fr) * 64 + sa1];
    }
    if (kt + 1 < NT) STAGE_HALF(kt + 1, 1);
    __builtin_amdgcn_s_barrier();
    asm volatile("s_waitcnt lgkmcnt(0)" ::: "memory");
    __builtin_amdgcn_sched_barrier(0);
    __builtin_amdgcn_s_setprio(1);
#pragma unroll
    for (int i = 0; i < 4; ++i)
#pragma unroll
      for (int j = 2; j < 4; ++j) {
        acc[i][j] = __builtin_amdgcn_mfma_f32_16x16x32_f16(a0[i], b0[j], acc[i][j], 0, 0, 0);
        acc[i][j] = __builtin_amdgcn_mfma_f32_16x16x32_f16(a1[i], b1[j], acc[i][j], 0, 0, 0);
      }
    __builtin_amdgcn_s_setprio(0);
    __builtin_amdgcn_s_barrier();

    // ---------------- phase 3: quadrant (i4-7, j2-3), 8 ds_reads -----------
#pragma unroll
    for (int i = 0; i < 4; ++i) {
      a0[i] = *(const v8h*)&Ab[(wm + 64 + i * 16 + fr) * 64 + sa0];
      a1[i] = *(const v8h*)&Ab[(wm + 64 + i * 16 + fr) * 64 + sa1];
    }
    __builtin_amdgcn_s_barrier();
    asm volatile("s_waitcnt lgkmcnt(0)" ::: "memory");
    __builtin_amdgcn_sched_barrier(0);
    __builtin_amdgcn_s_setprio(1);
#pragma unroll
    for (int i = 0; i < 4; ++i)
#pragma unroll
      for (int j = 2; j < 4; ++j) {
        acc[4 + i][j] = __builtin_amdgcn_mfma_f32_16x16x32_f16(a0[i], b0[j], acc[4 + i][j], 0, 0, 0);
        acc[4 + i][j] = __builtin_amdgcn_mfma_f32_16x16x32_f16(a1[i], b1[j], acc[4 + i][j], 0, 0, 0);
      }
    __builtin_amdgcn_s_setprio(0);
    __builtin_amdgcn_s_barrier();

    // ---------------- phase 4: quadrant (i4-7, j0-1), regs live ------------
    __builtin_amdgcn_s_setprio(1);
#pragma unroll
    for (int i = 0; i < 4; ++i)
#pragma unroll
      for (int j = 0; j < 2; ++j) {
        acc[4 + i][j] = __builtin_amdgcn_mfma_f32_16x16x32_f16(a0[i], b0[j], acc[4 + i][j], 0, 0, 0);
        acc[4 + i][j] = __builtin_amdgcn_mfma_f32_16x16x32_f16(a1[i], b1[j], acc[4 + i][j], 0, 0, 0);
      }
    __builtin_amdgcn_s_setprio(0);
    // Own slices of tile kt+1 (issued ph1/ph2) landed; barrier publishes all.
    asm volatile("s_waitcnt vmcnt(0)" ::: "memory");
    __builtin_amdgcn_sched_barrier(0);
    __builtin_amdgcn_s_barrier();
  }
#undef STAGE_HALF

  float* Cfb = Cf ? Cf + (long long)bz * sC : nullptr;
  _Float16* Chb = Chp ? Chp + (long long)bz * sC : nullptr;
#pragma unroll
  for (int i = 0; i < 8; ++i) {
#pragma unroll
    for (int j = 0; j < 4; ++j) {
#pragma unroll
      for (int r = 0; r < 4; ++r) {
        const int row = m0c + wm + i * 16 + fq * 4 + r;
        const int col = n0 + wn + j * 16 + fr;
        float v = acc[i][j][r];
        if (relu) v = fmaxf(v, 0.f);
        if (Cfb) Cfb[(long long)row * N + col] = v;
        if (Chb) Chb[(long long)row * N + col] = (_Float16)v;
      }
    }
  }
}

// ---------------------------------------------------------------------------
__global__ __launch_bounds__(256) void convert_all_kernel(
    const float* __restrict__ s0, _Float16* __restrict__ d0, int b0,  // k
    const float* __restrict__ s1, _Float16* __restrict__ d1, int b1,  // q
    const float* __restrict__ s2, _Float16* __restrict__ d2, int b2,  // Wk
    const float* __restrict__ s3, _Float16* __restrict__ d3)          // Wq
{
  int blk = blockIdx.x;
  const float* src;
  _Float16* dst;
  if (blk < b0)           { src = s0; dst = d0; }
  else if (blk < b0 + b1) { src = s1; dst = d1; blk -= b0; }
  else if (blk < b0 + b1 + b2) { src = s2; dst = d2; blk -= b0 + b1; }
  else                    { src = s3; dst = d3; blk -= b0 + b1 + b2; }
  const long long i = ((long long)blk * 256 + threadIdx.x) * 4;
  const float4 v = *(const float4*)(src + i);
  v4h o = {(_Float16)v.x, (_Float16)v.y, (_Float16)v.z, (_Float16)v.w};
  *(v4h*)(dst + i) = o;
}

// q [B,Q,H] fp32 -> qT [B,H,Q] fp16, 64x64 tiles
__global__ __launch_bounds__(256) void transpose_f16_kernel(
    const float* __restrict__ q, _Float16* __restrict__ qT, int Q, int H)
{
  __shared__ float tile[64][65];
  const float* qb = q + (long long)blockIdx.z * Q * H;
  _Float16* qTb = qT + (long long)blockIdx.z * H * Q;
  const int q0 = blockIdx.x * 64, h0 = blockIdx.y * 64;
  const int t = threadIdx.x;
  const int tr = t >> 4, tc = (t & 15) << 2;
#pragma unroll
  for (int i = 0; i < 4; ++i) {
    const float4 v = *(const float4*)(qb + (long long)(q0 + tr + i * 16) * H + h0 + tc);
    tile[tr + i * 16][tc + 0] = v.x;
    tile[tr + i * 16][tc + 1] = v.y;
    tile[tr + i * 16][tc + 2] = v.z;
    tile[tr + i * 16][tc + 3] = v.w;
  }
  __syncthreads();
#pragma unroll
  for (int i = 0; i < 4; ++i) {
    const int hl = tr + i * 16;
    const int ql = tc;
    v4h o = {(_Float16)tile[ql + 0][hl], (_Float16)tile[ql + 1][hl],
             (_Float16)tile[ql + 2][hl], (_Float16)tile[ql + 3][hl]};
    *(v4h*)(qTb + (long long)(h0 + hl) * Q + q0 + ql) = o;
  }
}

// softmax rows of S [B*P, Q] fp32 in place; also write fp16 copy
__global__ __launch_bounds__(256) void softmax_rows_kernel(
    float* __restrict__ S, _Float16* __restrict__ S16,
    const unsigned char* __restrict__ qmask, int Q, int P)
{
  const long long row = blockIdx.x;       // b*P + p
  const int b = (int)(row / P);
  float* s = S + row * (long long)Q;
  const unsigned char* msk = qmask + (long long)b * Q;
  const int t = threadIdx.x;
  float4 v = *(const float4*)(s + (t << 2));
  float vals[4] = {v.x, v.y, v.z, v.w};
#pragma unroll
  for (int j = 0; j < 4; ++j)
    if (msk[(t << 2) + j]) vals[j] = -INFINITY;

  __shared__ float red[8];
  const int wid = t >> 6, lid = t & 63;

  float mx = fmaxf(fmaxf(vals[0], vals[1]), fmaxf(vals[2], vals[3]));
#pragma unroll
  for (int o = 32; o > 0; o >>= 1) mx = fmaxf(mx, __shfl_xor(mx, o, 64));
  if (lid == 0) red[wid] = mx;
  __syncthreads();
  mx = fmaxf(fmaxf(red[0], red[1]), fmaxf(red[2], red[3]));

  float e[4];
  float sum = 0.f;
#pragma unroll
  for (int j = 0; j < 4; ++j) { e[j] = __expf(vals[j] - mx); sum += e[j]; }
#pragma unroll
  for (int o = 32; o > 0; o >>= 1) sum += __shfl_xor(sum, o, 64);
  __syncthreads();
  if (lid == 0) red[4 + wid] = sum;
  __syncthreads();
  sum = red[4] + red[5] + red[6] + red[7];
  const float inv = 1.f / sum;

  float4 o;
  o.x = e[0] * inv; o.y = e[1] * inv; o.z = e[2] * inv; o.w = e[3] * inv;
  *(float4*)(s + (t << 2)) = o;
  v4h oh = {(_Float16)o.x, (_Float16)o.y, (_Float16)o.z, (_Float16)o.w};
  *(v4h*)(S16 + row * (long long)Q + (t << 2)) = oh;
}

// ---------------------------------------------------------------------------
extern "C" void kernel_launch(void* const* d_in, const int* in_sizes, int n_in,
                              void* d_out, int out_size, void* d_ws, size_t ws_size,
                              hipStream_t stream)
{
  const int B = 8, P = 2048, Q = 1024, H = 1024;
  const float* k  = (const float*)d_in[0];
  const float* q  = (const float*)d_in[1];
  const unsigned char* qmask = (const unsigned char*)d_in[2];
  const float* Wk = (const float*)d_in[3];
  const float* Wq = (const float*)d_in[4];

  float* ctx    = (float*)d_out;                  // [B,P,H] fp32
  float* alphas = ctx + (size_t)B * P * H;        // [B,P,Q] fp32

  _Float16* pkey16 = (_Float16*)d_out;            // parked in ctx region

  char* wsb = (char*)d_ws;
  _Float16* qkey16   = (_Float16*)(wsb);                        // 16.78 MB
  _Float16* k16      = (_Float16*)(wsb + 16777216);             // 33.55 MB
  _Float16* alphas16 = k16;                                     // k16 dead after proj
  _Float16* q16      = (_Float16*)(wsb + 16777216 + 33554432);  // 16.78 MB, contiguous after k16
  _Float16* qT16     = q16;                                     // q16 dead after proj
  _Float16* Wk16     = (_Float16*)(wsb + 67108864);
  _Float16* Wq16     = (_Float16*)(wsb + 69206016);

  const long long nK = (long long)B * P * H;   // 16.78M
  const long long nQ = (long long)B * Q * H;   // 8.39M
  const long long nW = (long long)H * H;       // 1.05M

  // 1. fused converts
  const int bK = (int)(nK / 1024), bQ = (int)(nQ / 1024), bW = (int)(nW / 1024);
  convert_all_kernel<<<bK + bQ + 2 * bW, 256, 0, stream>>>(
      k, k16, bK, q, q16, bQ, Wk, Wk16, bW, Wq, Wq16);

  const size_t LDSB = 131072;   // 128 KB dynamic LDS
  // 2. fused projections: A = [k16 ; q16] contiguous [24576 x 1024].
  //    mt 0..63  -> relu(k16 @ Wk16^T) -> pkey16 ; mt 64..95 -> qkey16
  gemm_nt_f16_256<<<96 * 4, 512, LDSB, stream>>>(
      k16, Wk16, nullptr, pkey16, Wq16, qkey16, 64,
      H, H, 96, 4, 0LL, 0LL, 0LL, 1);
  // 3. scores = pkey16 @ qkey16^T (batched) -> alphas slice fp32
  gemm_nt_f16_256<<<8 * 4 * B, 512, LDSB, stream>>>(
      pkey16, qkey16, alphas, nullptr, qkey16, nullptr, 1 << 28,
      Q, H, 8, 4, (long long)P * H, (long long)Q * H, (long long)P * Q, 0);
  // 4. qT16 = q^T fp16 (overwrites q16; q16 dead after step 2)
  transpose_f16_kernel<<<dim3(Q / 64, H / 64, B), 256, 0, stream>>>(q, qT16, Q, H);
  // 5. softmax in place + fp16 copy (overwrites k16)
  softmax_rows_kernel<<<B * P, 256, 0, stream>>>(alphas, alphas16, qmask, Q, P);
  // 6. ctx = alphas16 @ qT16^T (batched NT) -> d_out base
  gemm_nt_f16_256<<<8 * 4 * B, 512, LDSB, stream>>>(
      alphas16, qT16, ctx, nullptr, qT16, nullptr, 1 << 28,
      H, Q, 8, 4, (long long)P * Q, (long long)H * Q, (long long)P * H, 0);
}